// Round 3
// baseline (62.915 us; speedup 1.0000x reference)
//
#include <hip/hip_runtime.h>
#include <hip/hip_bf16.h>

#define NTHREADS 320
#define EPSF 1e-5f
// fold (1/sqrt(2)) * log2(e) into q so score -> exp2 directly
#define QSCALE 1.0201606003163899f

typedef float v2f __attribute__((ext_vector_type(2)));

#if __has_builtin(__builtin_amdgcn_exp2f)
#define EXP2F(x) __builtin_amdgcn_exp2f(x)
#else
extern "C" __device__ float __ocml_native_exp2_f32(float);
#define EXP2F(x) __ocml_native_exp2_f32(x)
#endif

__device__ __forceinline__ void two_qubit(float xa, float xb, float pa, float pb,
                                          float cg, float sg, float ch, float sh,
                                          float& z0, float& z1) {
    const float ha = 0.5f * (xa + pa);
    const float hb = 0.5f * (xb + pb);
    float sa, ca, sb, cb;
    __sincosf(ha, &sa, &ca);
    __sincosf(hb, &sb, &cb);
    // product state, then CNOT(0,1) swaps |10> <-> |11>
    const float p00 = ca * cb, p01 = ca * sb;
    const float p10 = sa * sb, p11 = sa * cb;  // post-swap
    const float q00 = cg * p00 - sg * p10;
    const float q10 = sg * p00 + cg * p10;
    const float q01 = cg * p01 - sg * p11;
    const float q11 = sg * p01 + cg * p11;
    const float r00 = ch * q00 - sh * q01;
    const float r01 = sh * q00 + ch * q01;
    const float r10 = ch * q10 - sh * q11;
    const float r11 = sh * q10 + ch * q11;
    const float a = r00 * r00, b = r01 * r01, c = r10 * r10, d = r11 * r11;
    z0 = a + b - c - d;
    z1 = a - b + c - d;
}

__global__ __launch_bounds__(NTHREADS)
void quanv_fused(const float* __restrict__ x,
                 const float* __restrict__ qparams,
                 const float* __restrict__ in_w,
                 const float* __restrict__ in_b,
                 const float* __restrict__ out_w,
                 const float* __restrict__ out_b,
                 const float* __restrict__ lnw,
                 const float* __restrict__ lnb,
                 const float* __restrict__ lin_w,
                 const float* __restrict__ lin_b,
                 float* __restrict__ out)
{
    // img (staging) and flat (LN output) have disjoint live ranges -> overlay
    __shared__ __align__(16) float img_flat[784];
    __shared__ __align__(8) float q0s[2][196], q1s[2][196];  // q pre-scaled by QSCALE
    __shared__ __align__(8) float k0s[2][196], k1s[2][196];  // SoA K per head
    __shared__ __align__(8) float v0s[2][196], v1s[2][196];  // SoA V per head
    __shared__ __align__(16) float ob[196][4];               // attention output
    __shared__ float w_in[48], b_in[12], w_out[16], b_out[4];
    __shared__ float s_lnw[4], s_lnb[4], s_linb[10];
    __shared__ float qc[8];             // cos/sin of qparams[4..7]/2
    __shared__ float qp[4];             // qparams[0..3]
    __shared__ float wsum[5][10];
    __shared__ float logits_s[10];
    __shared__ float lse_s;

    const int tid = threadIdx.x;
    const int bid = blockIdx.x;

    // ---- stage image (float4) + weights into LDS ----
    const float4* xb4 = (const float4*)(x + (size_t)bid * 784);
    if (tid < 196) ((float4*)img_flat)[tid] = xb4[tid];
    if (tid < 48) w_in[tid] = in_w[tid];
    {
        int t = tid - 64;  if (t >= 0 && t < 12) b_in[t] = in_b[t];
        t = tid - 80;      if (t >= 0 && t < 16) w_out[t] = out_w[t];
        t = tid - 96;      if (t >= 0 && t < 4)  b_out[t] = out_b[t];
        t = tid - 112;     if (t >= 0 && t < 4)  s_lnw[t] = lnw[t];
        t = tid - 128;     if (t >= 0 && t < 4)  s_lnb[t] = lnb[t];
        t = tid - 144;     if (t >= 0 && t < 10) s_linb[t] = lin_b[t];
        t = tid - 160;     if (t >= 0 && t < 4)  qp[t] = qparams[t];
        t = tid - 176;
        if (t >= 0 && t < 4) {
            const float g = 0.5f * qparams[4 + t];
            float sg, cg;
            __sincosf(g, &sg, &cg);
            qc[2 * t] = cg;
            qc[2 * t + 1] = sg;
        }
    }
    __syncthreads();

    // ---- quantum features + QKV projection (thread per patch) ----
    if (tid < 196) {
        const int l = tid;
        const int r = l / 14, c = l % 14;
        const float p0 = img_flat[(2 * r) * 28 + 2 * c];
        const float p1 = img_flat[(2 * r) * 28 + 2 * c + 1];
        const float p2 = img_flat[(2 * r + 1) * 28 + 2 * c];
        const float p3 = img_flat[(2 * r + 1) * 28 + 2 * c + 1];
        float z0, z1, z2, z3;
        two_qubit(p0, p1, qp[0], qp[1], qc[0], qc[1], qc[2], qc[3], z0, z1);
        two_qubit(p2, p3, qp[2], qp[3], qc[4], qc[5], qc[6], qc[7], z2, z3);
        float a[12];
        #pragma unroll
        for (int j = 0; j < 12; ++j)
            a[j] = b_in[j] + z0 * w_in[j * 4] + z1 * w_in[j * 4 + 1]
                 + z2 * w_in[j * 4 + 2] + z3 * w_in[j * 4 + 3];
        q0s[0][l] = a[0] * QSCALE;  q1s[0][l] = a[1] * QSCALE;   // head 0
        q0s[1][l] = a[2] * QSCALE;  q1s[1][l] = a[3] * QSCALE;   // head 1
        k0s[0][l] = a[4];  k1s[0][l] = a[5];
        k0s[1][l] = a[6];  k1s[1][l] = a[7];
        v0s[0][l] = a[8];  v1s[0][l] = a[9];
        v0s[1][l] = a[10]; v1s[1][l] = a[11];
    }
    __syncthreads();

    // ---- attention: single pass (bounded scores, exp2-folded),
    //      2 lanes per (h,l) row, 49 packed pair-iters each ----
    for (int id = tid; id < 784; id += NTHREADS) {
        const int rowid = id >> 1;      // 0..391
        const int half  = id & 1;
        const int l = rowid % 196;
        const int h = rowid / 196;
        const float q0 = q0s[h][l];
        const float q1 = q1s[h][l];
        const int m0 = half * 98;       // even -> v2f aligned
        const v2f* k0p = (const v2f*)&k0s[h][m0];
        const v2f* k1p = (const v2f*)&k1s[h][m0];
        const v2f* v0p = (const v2f*)&v0s[h][m0];
        const v2f* v1p = (const v2f*)&v1s[h][m0];
        v2f sum2 = {0.f, 0.f}, acc0 = {0.f, 0.f}, acc1 = {0.f, 0.f};
        #pragma unroll 7
        for (int i = 0; i < 49; ++i) {
            const v2f k0 = k0p[i], k1 = k1p[i];
            const v2f s = k0 * q0 + k1 * q1;   // v_pk_mul + v_pk_fma
            v2f e;
            e.x = EXP2F(s.x);
            e.y = EXP2F(s.y);
            sum2 += e;                          // v_pk_add
            acc0 += e * v0p[i];                 // v_pk_fma
            acc1 += e * v1p[i];                 // v_pk_fma
        }
        float sum = sum2.x + sum2.y;
        float a0  = acc0.x + acc0.y;
        float a1  = acc1.x + acc1.y;
        sum += __shfl_xor(sum, 1);
        a0  += __shfl_xor(a0, 1);
        a1  += __shfl_xor(a1, 1);
        const float inv = 1.0f / sum;
        if (half == 0) ob[l][2 * h]     = a0 * inv;
        else           ob[l][2 * h + 1] = a1 * inv;
    }
    __syncthreads();

    // ---- out-proj + LayerNorm (thread per row), write transposed layout ----
    if (tid < 196) {
        const int l = tid;
        const float4 f = *(const float4*)ob[l];
        const float f0 = f.x, f1 = f.y, f2 = f.z, f3 = f.w;
        const float e0 = b_out[0] + f0 * w_out[0]  + f1 * w_out[1]  + f2 * w_out[2]  + f3 * w_out[3];
        const float e1 = b_out[1] + f0 * w_out[4]  + f1 * w_out[5]  + f2 * w_out[6]  + f3 * w_out[7];
        const float e2 = b_out[2] + f0 * w_out[8]  + f1 * w_out[9]  + f2 * w_out[10] + f3 * w_out[11];
        const float e3 = b_out[3] + f0 * w_out[12] + f1 * w_out[13] + f2 * w_out[14] + f3 * w_out[15];
        const float mu = 0.25f * (e0 + e1 + e2 + e3);
        const float d0 = e0 - mu, d1 = e1 - mu, d2 = e2 - mu, d3 = e3 - mu;
        const float var = 0.25f * (d0 * d0 + d1 * d1 + d2 * d2 + d3 * d3);
        const float rs = rsqrtf(var + EPSF);
        img_flat[0 * 196 + l] = d0 * rs * s_lnw[0] + s_lnb[0];
        img_flat[1 * 196 + l] = d1 * rs * s_lnw[1] + s_lnb[1];
        img_flat[2 * 196 + l] = d2 * rs * s_lnw[2] + s_lnb[2];
        img_flat[3 * 196 + l] = d3 * rs * s_lnw[3] + s_lnb[3];
    }
    __syncthreads();

    // ---- final linear (10 x 784), float4 per thread + log_softmax ----
    float part[10];
    #pragma unroll
    for (int j = 0; j < 10; ++j) part[j] = 0.f;
    if (tid < 196) {
        const float4 f = ((const float4*)img_flat)[tid];
        const float4* lw = (const float4*)lin_w + tid;
        #pragma unroll
        for (int j = 0; j < 10; ++j) {
            const float4 w = lw[j * 196];
            part[j] = f.x * w.x + f.y * w.y + f.z * w.z + f.w * w.w;
        }
    }
    const int lane = tid & 63, wv = tid >> 6;
    #pragma unroll
    for (int j = 0; j < 10; ++j) {
        float v = part[j];
        #pragma unroll
        for (int off = 32; off > 0; off >>= 1) v += __shfl_down(v, off);
        if (lane == 0) wsum[wv][j] = v;
    }
    __syncthreads();
    if (tid < 10)
        logits_s[tid] = wsum[0][tid] + wsum[1][tid] + wsum[2][tid]
                      + wsum[3][tid] + wsum[4][tid] + s_linb[tid];
    __syncthreads();
    if (tid == 0) {
        float mx = logits_s[0];
        #pragma unroll
        for (int j = 1; j < 10; ++j) mx = fmaxf(mx, logits_s[j]);
        float se = 0.f;
        #pragma unroll
        for (int j = 0; j < 10; ++j) se += __expf(logits_s[j] - mx);
        lse_s = mx + __logf(se);
    }
    __syncthreads();
    if (tid < 10) out[(size_t)bid * 10 + tid] = logits_s[tid] - lse_s;
}

extern "C" void kernel_launch(void* const* d_in, const int* in_sizes, int n_in,
                              void* d_out, int out_size, void* d_ws, size_t ws_size,
                              hipStream_t stream) {
    const float* x        = (const float*)d_in[0];
    const float* qparams  = (const float*)d_in[1];
    const float* in_w     = (const float*)d_in[2];
    const float* in_b     = (const float*)d_in[3];
    const float* out_w    = (const float*)d_in[4];
    const float* out_b    = (const float*)d_in[5];
    const float* lnw      = (const float*)d_in[6];
    const float* lnb      = (const float*)d_in[7];
    const float* lin_w    = (const float*)d_in[8];
    const float* lin_b    = (const float*)d_in[9];
    float* out            = (float*)d_out;

    const int B = in_sizes[0] / 784;
    hipLaunchKernelGGL(quanv_fused, dim3(B), dim3(NTHREADS), 0, stream,
                       x, qparams, in_w, in_b, out_w, out_b, lnw, lnb, lin_w, lin_b, out);
}

// Round 4
// 53.307 us; speedup vs baseline: 1.1802x; 1.1802x over previous
//
#include <hip/hip_runtime.h>
#include <hip/hip_bf16.h>

#define NTHREADS 256
#define EPSF 1e-5f
// fold (1/sqrt(2)) * log2(e) into q so score feeds v_exp_f32 (exp2) directly
#define QSCALE 1.0201606003163899f

typedef float v2f __attribute__((ext_vector_type(2)));

#if __has_builtin(__builtin_amdgcn_exp2f)
#define EXP2F(x) __builtin_amdgcn_exp2f(x)
#else
extern "C" __device__ float __ocml_native_exp2_f32(float);
#define EXP2F(x) __ocml_native_exp2_f32(x)
#endif

__device__ __forceinline__ void two_qubit(float xa, float xb, float pa, float pb,
                                          float cg, float sg, float ch, float sh,
                                          float& z0, float& z1) {
    const float ha = 0.5f * (xa + pa);
    const float hb = 0.5f * (xb + pb);
    float sa, ca, sb, cb;
    __sincosf(ha, &sa, &ca);
    __sincosf(hb, &sb, &cb);
    // product state, then CNOT(0,1) swaps |10> <-> |11>
    const float p00 = ca * cb, p01 = ca * sb;
    const float p10 = sa * sb, p11 = sa * cb;  // post-swap
    const float q00 = cg * p00 - sg * p10;
    const float q10 = sg * p00 + cg * p10;
    const float q01 = cg * p01 - sg * p11;
    const float q11 = sg * p01 + cg * p11;
    const float r00 = ch * q00 - sh * q01;
    const float r01 = sh * q00 + ch * q01;
    const float r10 = ch * q10 - sh * q11;
    const float r11 = sh * q10 + ch * q11;
    const float a = r00 * r00, b = r01 * r01, c = r10 * r10, d = r11 * r11;
    z0 = a + b - c - d;
    z1 = a - b + c - d;
}

__global__ __launch_bounds__(NTHREADS)
void quanv_fused(const float* __restrict__ x,
                 const float* __restrict__ qparams,
                 const float* __restrict__ in_w,
                 const float* __restrict__ in_b,
                 const float* __restrict__ out_w,
                 const float* __restrict__ out_b,
                 const float* __restrict__ lnw,
                 const float* __restrict__ lnb,
                 const float* __restrict__ lin_w,
                 const float* __restrict__ lin_b,
                 float* __restrict__ out)
{
    // img (staging) and flat (LN output) have disjoint live ranges -> overlay
    __shared__ __align__(16) float img_flat[784];
    __shared__ __align__(8) float q0s[2][196], q1s[2][196];  // q pre-scaled by QSCALE
    __shared__ __align__(8) float k0s[2][196], k1s[2][196];  // SoA K per head
    __shared__ __align__(8) float v0s[2][196], v1s[2][196];  // SoA V per head
    __shared__ __align__(16) float ob[196][4];               // attention output
    __shared__ float w_in[48], b_in[12], w_out[16], b_out[4];
    __shared__ float s_lnw[4], s_lnb[4], s_linb[10];
    __shared__ float qc[8];             // cos/sin of qparams[4..7]/2
    __shared__ float qp[4];             // qparams[0..3]
    __shared__ float wsum[4][10];
    __shared__ float logits_s[10];
    __shared__ float lse_s;

    const int tid = threadIdx.x;
    const int bid = blockIdx.x;

    // ---- stage image (float4) + weights into LDS ----
    const float4* xb4 = (const float4*)(x + (size_t)bid * 784);
    if (tid < 196) ((float4*)img_flat)[tid] = xb4[tid];
    if (tid < 48) w_in[tid] = in_w[tid];
    {
        int t = tid - 64;  if (t >= 0 && t < 12) b_in[t] = in_b[t];
        t = tid - 80;      if (t >= 0 && t < 16) w_out[t] = out_w[t];
        t = tid - 96;      if (t >= 0 && t < 4)  b_out[t] = out_b[t];
        t = tid - 112;     if (t >= 0 && t < 4)  s_lnw[t] = lnw[t];
        t = tid - 128;     if (t >= 0 && t < 4)  s_lnb[t] = lnb[t];
        t = tid - 144;     if (t >= 0 && t < 10) s_linb[t] = lin_b[t];
        t = tid - 160;     if (t >= 0 && t < 4)  qp[t] = qparams[t];
        t = tid - 176;
        if (t >= 0 && t < 4) {
            const float g = 0.5f * qparams[4 + t];
            float sg, cg;
            __sincosf(g, &sg, &cg);
            qc[2 * t] = cg;
            qc[2 * t + 1] = sg;
        }
    }
    __syncthreads();

    // ---- quantum features + QKV projection (thread per patch) ----
    if (tid < 196) {
        const int l = tid;
        const int r = l / 14, c = l % 14;
        const float p0 = img_flat[(2 * r) * 28 + 2 * c];
        const float p1 = img_flat[(2 * r) * 28 + 2 * c + 1];
        const float p2 = img_flat[(2 * r + 1) * 28 + 2 * c];
        const float p3 = img_flat[(2 * r + 1) * 28 + 2 * c + 1];
        float z0, z1, z2, z3;
        two_qubit(p0, p1, qp[0], qp[1], qc[0], qc[1], qc[2], qc[3], z0, z1);
        two_qubit(p2, p3, qp[2], qp[3], qc[4], qc[5], qc[6], qc[7], z2, z3);
        float a[12];
        #pragma unroll
        for (int j = 0; j < 12; ++j)
            a[j] = b_in[j] + z0 * w_in[j * 4] + z1 * w_in[j * 4 + 1]
                 + z2 * w_in[j * 4 + 2] + z3 * w_in[j * 4 + 3];
        q0s[0][l] = a[0] * QSCALE;  q1s[0][l] = a[1] * QSCALE;   // head 0
        q0s[1][l] = a[2] * QSCALE;  q1s[1][l] = a[3] * QSCALE;   // head 1
        k0s[0][l] = a[4];  k1s[0][l] = a[5];
        k0s[1][l] = a[6];  k1s[1][l] = a[7];
        v0s[0][l] = a[8];  v1s[0][l] = a[9];
        v0s[1][l] = a[10]; v1s[1][l] = a[11];
    }
    __syncthreads();

    // ---- attention: single pass (bounded scores, exp2-folded) ----
    // items 0..767: 3 exact passes, 2 lanes per (h,l) row, 49 pair-iters each
    #pragma unroll
    for (int pass = 0; pass < 3; ++pass) {
        const int id = tid + pass * NTHREADS;
        const int rowid = id >> 1;
        const int half  = id & 1;
        const int l = rowid % 196;
        const int h = rowid / 196;
        const float q0 = q0s[h][l];
        const float q1 = q1s[h][l];
        const v2f* k0p = (const v2f*)&k0s[h][half * 98];
        const v2f* k1p = (const v2f*)&k1s[h][half * 98];
        const v2f* v0p = (const v2f*)&v0s[h][half * 98];
        const v2f* v1p = (const v2f*)&v1s[h][half * 98];
        v2f sum2 = {0.f, 0.f}, acc0 = {0.f, 0.f}, acc1 = {0.f, 0.f};
        #pragma unroll 7
        for (int i = 0; i < 49; ++i) {
            const v2f s = k0p[i] * q0 + k1p[i] * q1;
            v2f e;
            e.x = EXP2F(s.x);
            e.y = EXP2F(s.y);
            sum2 += e;
            acc0 += e * v0p[i];
            acc1 += e * v1p[i];
        }
        float sum = sum2.x + sum2.y;
        float a0  = acc0.x + acc0.y;
        float a1  = acc1.x + acc1.y;
        sum += __shfl_xor(sum, 1);
        a0  += __shfl_xor(a0, 1);
        a1  += __shfl_xor(a1, 1);
        if (half == 0) {
            const float inv = 1.0f / sum;
            *(float2*)&ob[l][2 * h] = make_float2(a0 * inv, a1 * inv);
        }
    }
    // tail rows 384..391 (h=1, l=188..195): 8 lanes per row, 12-13 pair-iters
    if (tid < 64) {
        const int row = 384 + (tid >> 3);
        const int e8  = tid & 7;
        const int l = row % 196;
        const int h = row / 196;
        const int start = (e8 < 2) ? e8 * 13 : 26 + (e8 - 2) * 12;
        const int len   = (e8 < 2) ? 13 : 12;
        const float q0 = q0s[h][l];
        const float q1 = q1s[h][l];
        const v2f* k0p = (const v2f*)&k0s[h][0];
        const v2f* k1p = (const v2f*)&k1s[h][0];
        const v2f* v0p = (const v2f*)&v0s[h][0];
        const v2f* v1p = (const v2f*)&v1s[h][0];
        v2f sum2 = {0.f, 0.f}, acc0 = {0.f, 0.f}, acc1 = {0.f, 0.f};
        for (int i = start; i < start + len; ++i) {
            const v2f s = k0p[i] * q0 + k1p[i] * q1;
            v2f e;
            e.x = EXP2F(s.x);
            e.y = EXP2F(s.y);
            sum2 += e;
            acc0 += e * v0p[i];
            acc1 += e * v1p[i];
        }
        float sum = sum2.x + sum2.y;
        float a0  = acc0.x + acc0.y;
        float a1  = acc1.x + acc1.y;
        #pragma unroll
        for (int off = 1; off < 8; off <<= 1) {
            sum += __shfl_xor(sum, off);
            a0  += __shfl_xor(a0, off);
            a1  += __shfl_xor(a1, off);
        }
        if (e8 == 0) {
            const float inv = 1.0f / sum;
            *(float2*)&ob[l][2 * h] = make_float2(a0 * inv, a1 * inv);
        }
    }
    __syncthreads();

    // ---- out-proj + LayerNorm (thread per row), write transposed layout ----
    if (tid < 196) {
        const int l = tid;
        const float4 f = *(const float4*)ob[l];
        const float f0 = f.x, f1 = f.y, f2 = f.z, f3 = f.w;
        const float e0 = b_out[0] + f0 * w_out[0]  + f1 * w_out[1]  + f2 * w_out[2]  + f3 * w_out[3];
        const float e1 = b_out[1] + f0 * w_out[4]  + f1 * w_out[5]  + f2 * w_out[6]  + f3 * w_out[7];
        const float e2 = b_out[2] + f0 * w_out[8]  + f1 * w_out[9]  + f2 * w_out[10] + f3 * w_out[11];
        const float e3 = b_out[3] + f0 * w_out[12] + f1 * w_out[13] + f2 * w_out[14] + f3 * w_out[15];
        const float mu = 0.25f * (e0 + e1 + e2 + e3);
        const float d0 = e0 - mu, d1 = e1 - mu, d2 = e2 - mu, d3 = e3 - mu;
        const float var = 0.25f * (d0 * d0 + d1 * d1 + d2 * d2 + d3 * d3);
        const float rs = rsqrtf(var + EPSF);
        img_flat[0 * 196 + l] = d0 * rs * s_lnw[0] + s_lnb[0];
        img_flat[1 * 196 + l] = d1 * rs * s_lnw[1] + s_lnb[1];
        img_flat[2 * 196 + l] = d2 * rs * s_lnw[2] + s_lnb[2];
        img_flat[3 * 196 + l] = d3 * rs * s_lnw[3] + s_lnb[3];
    }
    __syncthreads();

    // ---- final linear (10 x 784), float4 per thread + log_softmax ----
    float part[10];
    #pragma unroll
    for (int j = 0; j < 10; ++j) part[j] = 0.f;
    if (tid < 196) {
        const float4 f = ((const float4*)img_flat)[tid];
        const float4* lw = (const float4*)lin_w + tid;
        #pragma unroll
        for (int j = 0; j < 10; ++j) {
            const float4 w = lw[j * 196];
            part[j] = f.x * w.x + f.y * w.y + f.z * w.z + f.w * w.w;
        }
    }
    const int lane = tid & 63, wv = tid >> 6;
    #pragma unroll
    for (int j = 0; j < 10; ++j) {
        float v = part[j];
        #pragma unroll
        for (int off = 32; off > 0; off >>= 1) v += __shfl_down(v, off);
        if (lane == 0) wsum[wv][j] = v;
    }
    __syncthreads();
    if (tid < 10)
        logits_s[tid] = wsum[0][tid] + wsum[1][tid] + wsum[2][tid]
                      + wsum[3][tid] + s_linb[tid];
    __syncthreads();
    if (tid == 0) {
        float mx = logits_s[0];
        #pragma unroll
        for (int j = 1; j < 10; ++j) mx = fmaxf(mx, logits_s[j]);
        float se = 0.f;
        #pragma unroll
        for (int j = 0; j < 10; ++j) se += __expf(logits_s[j] - mx);
        lse_s = mx + __logf(se);
    }
    __syncthreads();
    if (tid < 10) out[(size_t)bid * 10 + tid] = logits_s[tid] - lse_s;
}

extern "C" void kernel_launch(void* const* d_in, const int* in_sizes, int n_in,
                              void* d_out, int out_size, void* d_ws, size_t ws_size,
                              hipStream_t stream) {
    const float* x        = (const float*)d_in[0];
    const float* qparams  = (const float*)d_in[1];
    const float* in_w     = (const float*)d_in[2];
    const float* in_b     = (const float*)d_in[3];
    const float* out_w    = (const float*)d_in[4];
    const float* out_b    = (const float*)d_in[5];
    const float* lnw      = (const float*)d_in[6];
    const float* lnb      = (const float*)d_in[7];
    const float* lin_w    = (const float*)d_in[8];
    const float* lin_b    = (const float*)d_in[9];
    float* out            = (float*)d_out;

    const int B = in_sizes[0] / 784;
    hipLaunchKernelGGL(quanv_fused, dim3(B), dim3(NTHREADS), 0, stream,
                       x, qparams, in_w, in_b, out_w, out_b, lnw, lnb, lin_w, lin_b, out);
}

// Round 5
// 41.511 us; speedup vs baseline: 1.5156x; 1.2842x over previous
//
#include <hip/hip_runtime.h>
#include <hip/hip_bf16.h>

#define NTHREADS 256
#define EPSF 1e-5f
// fold (1/sqrt(2)) * log2(e) into q so score feeds v_exp_f32 (exp2) directly
#define QSCALE 1.0201606003163899f

typedef float v2f __attribute__((ext_vector_type(2)));
typedef float v4f __attribute__((ext_vector_type(4)));

#if __has_builtin(__builtin_amdgcn_exp2f)
#define EXP2F(x) __builtin_amdgcn_exp2f(x)
#else
extern "C" __device__ float __ocml_native_exp2_f32(float);
#define EXP2F(x) __ocml_native_exp2_f32(x)
#endif

__device__ __forceinline__ void two_qubit(float xa, float xb, float pa, float pb,
                                          float cg, float sg, float ch, float sh,
                                          float& z0, float& z1) {
    const float ha = 0.5f * (xa + pa);
    const float hb = 0.5f * (xb + pb);
    float sa, ca, sb, cb;
    __sincosf(ha, &sa, &ca);
    __sincosf(hb, &sb, &cb);
    // product state, then CNOT(0,1) swaps |10> <-> |11>
    const float p00 = ca * cb, p01 = ca * sb;
    const float p10 = sa * sb, p11 = sa * cb;  // post-swap
    const float q00 = cg * p00 - sg * p10;
    const float q10 = sg * p00 + cg * p10;
    const float q01 = cg * p01 - sg * p11;
    const float q11 = sg * p01 + cg * p11;
    const float r00 = ch * q00 - sh * q01;
    const float r01 = sh * q00 + ch * q01;
    const float r10 = ch * q10 - sh * q11;
    const float r11 = sh * q10 + ch * q11;
    const float a = r00 * r00, b = r01 * r01, c = r10 * r10, d = r11 * r11;
    z0 = a + b - c - d;
    z1 = a - b + c - d;
}

__global__ __launch_bounds__(NTHREADS)
void quanv_fused(const float* __restrict__ x,
                 const float* __restrict__ qparams,
                 const float* __restrict__ in_w,
                 const float* __restrict__ in_b,
                 const float* __restrict__ out_w,
                 const float* __restrict__ out_b,
                 const float* __restrict__ lnw,
                 const float* __restrict__ lnb,
                 const float* __restrict__ lin_w,
                 const float* __restrict__ lin_b,
                 float* __restrict__ out)
{
    // img (staging) and flat (LN output) have disjoint live ranges -> overlay
    __shared__ __align__(16) float img_flat[784];
    __shared__ __align__(8)  float2 qs[2][196];   // (q0,q1) pre-scaled by QSCALE
    __shared__ v4f kT[2][98];   // kT[h][i] = (k0[2i],k0[2i+1],k1[2i],k1[2i+1])
    __shared__ v4f vT[2][98];   // vT[h][i] = (v0[2i],v0[2i+1],v1[2i],v1[2i+1])
    __shared__ __align__(16) float ob[196][4];    // attention output
    __shared__ float w_in[48], b_in[12], w_out[16], b_out[4];
    __shared__ float s_lnw[4], s_lnb[4], s_linb[10];
    __shared__ float qc[8];             // cos/sin of qparams[4..7]/2
    __shared__ float qp[4];             // qparams[0..3]
    __shared__ float wsum[4][10];
    __shared__ float logits_s[10];
    __shared__ float lse_s;

    const int tid = threadIdx.x;
    const int bid = blockIdx.x;

    // ---- stage image (float4) + weights into LDS ----
    const float4* xb4 = (const float4*)(x + (size_t)bid * 784);
    if (tid < 196) ((float4*)img_flat)[tid] = xb4[tid];
    if (tid < 48) w_in[tid] = in_w[tid];
    {
        int t = tid - 64;  if (t >= 0 && t < 12) b_in[t] = in_b[t];
        t = tid - 80;      if (t >= 0 && t < 16) w_out[t] = out_w[t];
        t = tid - 96;      if (t >= 0 && t < 4)  b_out[t] = out_b[t];
        t = tid - 112;     if (t >= 0 && t < 4)  s_lnw[t] = lnw[t];
        t = tid - 128;     if (t >= 0 && t < 4)  s_lnb[t] = lnb[t];
        t = tid - 144;     if (t >= 0 && t < 10) s_linb[t] = lin_b[t];
        t = tid - 160;     if (t >= 0 && t < 4)  qp[t] = qparams[t];
        t = tid - 176;
        if (t >= 0 && t < 4) {
            const float g = 0.5f * qparams[4 + t];
            float sg, cg;
            __sincosf(g, &sg, &cg);
            qc[2 * t] = cg;
            qc[2 * t + 1] = sg;
        }
    }
    __syncthreads();

    // ---- quantum features + QKV projection (thread per patch) ----
    if (tid < 196) {
        const int l = tid;
        const int r = l / 14, c = l % 14;
        const float p0 = img_flat[(2 * r) * 28 + 2 * c];
        const float p1 = img_flat[(2 * r) * 28 + 2 * c + 1];
        const float p2 = img_flat[(2 * r + 1) * 28 + 2 * c];
        const float p3 = img_flat[(2 * r + 1) * 28 + 2 * c + 1];
        float z0, z1, z2, z3;
        two_qubit(p0, p1, qp[0], qp[1], qc[0], qc[1], qc[2], qc[3], z0, z1);
        two_qubit(p2, p3, qp[2], qp[3], qc[4], qc[5], qc[6], qc[7], z2, z3);
        float a[12];
        #pragma unroll
        for (int j = 0; j < 12; ++j)
            a[j] = b_in[j] + z0 * w_in[j * 4] + z1 * w_in[j * 4 + 1]
                 + z2 * w_in[j * 4 + 2] + z3 * w_in[j * 4 + 3];
        qs[0][l] = make_float2(a[0] * QSCALE, a[1] * QSCALE);   // head 0
        qs[1][l] = make_float2(a[2] * QSCALE, a[3] * QSCALE);   // head 1
        const int i4 = l >> 1, e = l & 1;
        ((float*)&kT[0][i4])[e]     = a[4];
        ((float*)&kT[0][i4])[2 + e] = a[5];
        ((float*)&kT[1][i4])[e]     = a[6];
        ((float*)&kT[1][i4])[2 + e] = a[7];
        ((float*)&vT[0][i4])[e]     = a[8];
        ((float*)&vT[0][i4])[2 + e] = a[9];
        ((float*)&vT[1][i4])[e]     = a[10];
        ((float*)&vT[1][i4])[2 + e] = a[11];
    }
    __syncthreads();

    // ---- attention (bounded scores, exp2-folded) ----
    // wave wv owns rows [wv*98, wv*98+98): h = wv>>1 wave-uniform.
    // lanes 0-31: m-pairs 0..48 of 32 rows; lanes 32-63: pairs 49..97 of same
    // rows; combine via shfl_xor(.,32). Tail 2 rows spread over all 64 lanes.
    const int wv = tid >> 6;
    const int lane = tid & 63;
    const int h = wv >> 1;
    const int lbase = (wv & 1) * 98;
    const int halfsel = lane >> 5;
    const int sub = lane & 31;
    const v4f* kTp = &kT[h][0];
    const v4f* vTp = &vT[h][0];
    #pragma unroll
    for (int p = 0; p < 3; ++p) {
        const int l = lbase + p * 32 + sub;
        const float2 q = qs[h][l];
        const int i0 = halfsel * 49;
        v2f sum2 = {0.f, 0.f}, acc0 = {0.f, 0.f}, acc1 = {0.f, 0.f};
        #pragma unroll 7
        for (int i = 0; i < 49; ++i) {
            const v4f kk = kTp[i0 + i];     // ds_read_b128, 2-addr broadcast
            const v4f vv = vTp[i0 + i];
            const v2f s = kk.xy * q.x + kk.zw * q.y;
            v2f e;
            e.x = EXP2F(s.x);
            e.y = EXP2F(s.y);
            sum2 += e;
            acc0 += e * vv.xy;
            acc1 += e * vv.zw;
        }
        float sum = sum2.x + sum2.y;
        float a0  = acc0.x + acc0.y;
        float a1  = acc1.x + acc1.y;
        sum += __shfl_xor(sum, 32);
        a0  += __shfl_xor(a0, 32);
        a1  += __shfl_xor(a1, 32);
        if (halfsel == 0) {
            const float inv = 1.0f / sum;
            *(float2*)&ob[l][2 * h] = make_float2(a0 * inv, a1 * inv);
        }
    }
    // tail: rows lbase+96, lbase+97; 16 lanes per (row,half)
    {
        const int grp = lane >> 4;          // 0..3
        const int sub16 = lane & 15;
        const int l = lbase + 96 + (grp >> 1);
        const int hs = grp & 1;
        const float2 q = qs[h][l];
        const int base = hs * 49;
        v2f sum2 = {0.f, 0.f}, acc0 = {0.f, 0.f}, acc1 = {0.f, 0.f};
        #pragma unroll
        for (int k = 0; k < 3; ++k) {
            const int i = base + sub16 + k * 16;
            const v4f kk = kTp[i];
            const v4f vv = vTp[i];
            const v2f s = kk.xy * q.x + kk.zw * q.y;
            v2f e;
            e.x = EXP2F(s.x);
            e.y = EXP2F(s.y);
            sum2 += e;
            acc0 += e * vv.xy;
            acc1 += e * vv.zw;
        }
        if (sub16 == 0) {   // 49th pair
            const int i = base + 48;
            const v4f kk = kTp[i];
            const v4f vv = vTp[i];
            const v2f s = kk.xy * q.x + kk.zw * q.y;
            v2f e;
            e.x = EXP2F(s.x);
            e.y = EXP2F(s.y);
            sum2 += e;
            acc0 += e * vv.xy;
            acc1 += e * vv.zw;
        }
        float sum = sum2.x + sum2.y;
        float a0  = acc0.x + acc0.y;
        float a1  = acc1.x + acc1.y;
        #pragma unroll
        for (int off = 1; off < 32; off <<= 1) {
            sum += __shfl_xor(sum, off);
            a0  += __shfl_xor(a0, off);
            a1  += __shfl_xor(a1, off);
        }
        if ((lane & 31) == 0) {
            const float inv = 1.0f / sum;
            *(float2*)&ob[l][2 * h] = make_float2(a0 * inv, a1 * inv);
        }
    }
    __syncthreads();

    // ---- out-proj + LayerNorm (thread per row), write transposed layout ----
    if (tid < 196) {
        const int l = tid;
        const float4 f = *(const float4*)ob[l];
        const float f0 = f.x, f1 = f.y, f2 = f.z, f3 = f.w;
        const float e0 = b_out[0] + f0 * w_out[0]  + f1 * w_out[1]  + f2 * w_out[2]  + f3 * w_out[3];
        const float e1 = b_out[1] + f0 * w_out[4]  + f1 * w_out[5]  + f2 * w_out[6]  + f3 * w_out[7];
        const float e2 = b_out[2] + f0 * w_out[8]  + f1 * w_out[9]  + f2 * w_out[10] + f3 * w_out[11];
        const float e3 = b_out[3] + f0 * w_out[12] + f1 * w_out[13] + f2 * w_out[14] + f3 * w_out[15];
        const float mu = 0.25f * (e0 + e1 + e2 + e3);
        const float d0 = e0 - mu, d1 = e1 - mu, d2 = e2 - mu, d3 = e3 - mu;
        const float var = 0.25f * (d0 * d0 + d1 * d1 + d2 * d2 + d3 * d3);
        const float rs = rsqrtf(var + EPSF);
        img_flat[0 * 196 + l] = d0 * rs * s_lnw[0] + s_lnb[0];
        img_flat[1 * 196 + l] = d1 * rs * s_lnw[1] + s_lnb[1];
        img_flat[2 * 196 + l] = d2 * rs * s_lnw[2] + s_lnb[2];
        img_flat[3 * 196 + l] = d3 * rs * s_lnw[3] + s_lnb[3];
    }
    __syncthreads();

    // ---- final linear (10 x 784), float4 per thread + log_softmax ----
    float part[10];
    #pragma unroll
    for (int j = 0; j < 10; ++j) part[j] = 0.f;
    if (tid < 196) {
        const float4 f = ((const float4*)img_flat)[tid];
        const float4* lw = (const float4*)lin_w + tid;
        #pragma unroll
        for (int j = 0; j < 10; ++j) {
            const float4 w = lw[j * 196];
            part[j] = f.x * w.x + f.y * w.y + f.z * w.z + f.w * w.w;
        }
    }
    const int wlane = tid & 63, wvv = tid >> 6;
    #pragma unroll
    for (int j = 0; j < 10; ++j) {
        float v = part[j];
        #pragma unroll
        for (int off = 32; off > 0; off >>= 1) v += __shfl_down(v, off);
        if (wlane == 0) wsum[wvv][j] = v;
    }
    __syncthreads();
    if (tid < 10)
        logits_s[tid] = wsum[0][tid] + wsum[1][tid] + wsum[2][tid]
                      + wsum[3][tid] + s_linb[tid];
    __syncthreads();
    if (tid == 0) {
        float mx = logits_s[0];
        #pragma unroll
        for (int j = 1; j < 10; ++j) mx = fmaxf(mx, logits_s[j]);
        float se = 0.f;
        #pragma unroll
        for (int j = 0; j < 10; ++j) se += __expf(logits_s[j] - mx);
        lse_s = mx + __logf(se);
    }
    __syncthreads();
    if (tid < 10) out[(size_t)bid * 10 + tid] = logits_s[tid] - lse_s;
}

extern "C" void kernel_launch(void* const* d_in, const int* in_sizes, int n_in,
                              void* d_out, int out_size, void* d_ws, size_t ws_size,
                              hipStream_t stream) {
    const float* x        = (const float*)d_in[0];
    const float* qparams  = (const float*)d_in[1];
    const float* in_w     = (const float*)d_in[2];
    const float* in_b     = (const float*)d_in[3];
    const float* out_w    = (const float*)d_in[4];
    const float* out_b    = (const float*)d_in[5];
    const float* lnw      = (const float*)d_in[6];
    const float* lnb      = (const float*)d_in[7];
    const float* lin_w    = (const float*)d_in[8];
    const float* lin_b    = (const float*)d_in[9];
    float* out            = (float*)d_out;

    const int B = in_sizes[0] / 784;
    hipLaunchKernelGGL(quanv_fused, dim3(B), dim3(NTHREADS), 0, stream,
                       x, qparams, in_w, in_b, out_w, out_b, lnw, lnb, lin_w, lin_b, out);
}

// Round 6
// 36.951 us; speedup vs baseline: 1.7027x; 1.1234x over previous
//
#include <hip/hip_runtime.h>
#include <hip/hip_bf16.h>

#define NTHREADS 256
#define EPSF 1e-5f
// fold (1/sqrt(2)) * log2(e) into q so score feeds v_exp_f32 (exp2) directly
#define QSCALE 1.0201606003163899f

typedef float v2f __attribute__((ext_vector_type(2)));
typedef float v4f __attribute__((ext_vector_type(4)));

#if __has_builtin(__builtin_amdgcn_exp2f)
#define EXP2F(x) __builtin_amdgcn_exp2f(x)
#else
extern "C" __device__ float __ocml_native_exp2_f32(float);
#define EXP2F(x) __ocml_native_exp2_f32(x)
#endif

__device__ __forceinline__ void two_qubit(float xa, float xb, float pa, float pb,
                                          float cg, float sg, float ch, float sh,
                                          float& z0, float& z1) {
    const float ha = 0.5f * (xa + pa);
    const float hb = 0.5f * (xb + pb);
    float sa, ca, sb, cb;
    __sincosf(ha, &sa, &ca);
    __sincosf(hb, &sb, &cb);
    // product state, then CNOT(0,1) swaps |10> <-> |11>
    const float p00 = ca * cb, p01 = ca * sb;
    const float p10 = sa * sb, p11 = sa * cb;  // post-swap
    const float q00 = cg * p00 - sg * p10;
    const float q10 = sg * p00 + cg * p10;
    const float q01 = cg * p01 - sg * p11;
    const float q11 = sg * p01 + cg * p11;
    const float r00 = ch * q00 - sh * q01;
    const float r01 = sh * q00 + ch * q01;
    const float r10 = ch * q10 - sh * q11;
    const float r11 = sh * q10 + ch * q11;
    const float a = r00 * r00, b = r01 * r01, c = r10 * r10, d = r11 * r11;
    z0 = a + b - c - d;
    z1 = a - b + c - d;
}

__global__ __launch_bounds__(NTHREADS)
void quanv_fused(const float* __restrict__ x,
                 const float* __restrict__ qparams,
                 const float* __restrict__ in_w,
                 const float* __restrict__ in_b,
                 const float* __restrict__ out_w,
                 const float* __restrict__ out_b,
                 const float* __restrict__ lnw,
                 const float* __restrict__ lnb,
                 const float* __restrict__ lin_w,
                 const float* __restrict__ lin_b,
                 float* __restrict__ out)
{
    // union buffer: img (staging, 784f) / partials (2352f) / flat (784f)
    // live ranges are made disjoint by __syncthreads + reg staging.
    __shared__ __align__(16) float uni[2352];
    __shared__ __align__(8)  float2 qs[2][196];   // (q0,q1) pre-scaled by QSCALE
    __shared__ v4f kT[2][98];   // kT[h][i] = (k0[2i],k0[2i+1],k1[2i],k1[2i+1])
    __shared__ v4f vT[2][98];
    __shared__ float w_in[48], b_in[12], w_out[16], b_out[4];
    __shared__ float s_lnw[4], s_lnb[4], s_linb[10];
    __shared__ float qc[8];             // cos/sin of qparams[4..7]/2
    __shared__ float qp[4];             // qparams[0..3]
    __shared__ float wsum[4][10];
    __shared__ float logits_s[10];
    __shared__ float lse_s;

    // partial views into uni: [h*392 + hs*196 + l]
    float* psum = uni;
    float* pa0  = uni + 784;
    float* pa1  = uni + 1568;

    const int tid = threadIdx.x;
    const int bid = blockIdx.x;

    // ---- stage image (float4) + weights into LDS ----
    const float4* xb4 = (const float4*)(x + (size_t)bid * 784);
    if (tid < 196) ((float4*)uni)[tid] = xb4[tid];
    if (tid < 48) w_in[tid] = in_w[tid];
    {
        int t = tid - 64;  if (t >= 0 && t < 12) b_in[t] = in_b[t];
        t = tid - 80;      if (t >= 0 && t < 16) w_out[t] = out_w[t];
        t = tid - 96;      if (t >= 0 && t < 4)  b_out[t] = out_b[t];
        t = tid - 112;     if (t >= 0 && t < 4)  s_lnw[t] = lnw[t];
        t = tid - 128;     if (t >= 0 && t < 4)  s_lnb[t] = lnb[t];
        t = tid - 144;     if (t >= 0 && t < 10) s_linb[t] = lin_b[t];
        t = tid - 160;     if (t >= 0 && t < 4)  qp[t] = qparams[t];
        t = tid - 176;
        if (t >= 0 && t < 4) {
            const float g = 0.5f * qparams[4 + t];
            float sg, cg;
            __sincosf(g, &sg, &cg);
            qc[2 * t] = cg;
            qc[2 * t + 1] = sg;
        }
    }
    __syncthreads();

    // ---- quantum features + QKV projection (thread per patch) ----
    if (tid < 196) {
        const int l = tid;
        const int r = l / 14, c = l % 14;
        const float p0 = uni[(2 * r) * 28 + 2 * c];
        const float p1 = uni[(2 * r) * 28 + 2 * c + 1];
        const float p2 = uni[(2 * r + 1) * 28 + 2 * c];
        const float p3 = uni[(2 * r + 1) * 28 + 2 * c + 1];
        float z0, z1, z2, z3;
        two_qubit(p0, p1, qp[0], qp[1], qc[0], qc[1], qc[2], qc[3], z0, z1);
        two_qubit(p2, p3, qp[2], qp[3], qc[4], qc[5], qc[6], qc[7], z2, z3);
        float a[12];
        #pragma unroll
        for (int j = 0; j < 12; ++j)
            a[j] = b_in[j] + z0 * w_in[j * 4] + z1 * w_in[j * 4 + 1]
                 + z2 * w_in[j * 4 + 2] + z3 * w_in[j * 4 + 3];
        qs[0][l] = make_float2(a[0] * QSCALE, a[1] * QSCALE);   // head 0
        qs[1][l] = make_float2(a[2] * QSCALE, a[3] * QSCALE);   // head 1
        const int i4 = l >> 1, e = l & 1;
        ((float*)&kT[0][i4])[e]     = a[4];
        ((float*)&kT[0][i4])[2 + e] = a[5];
        ((float*)&kT[1][i4])[e]     = a[6];
        ((float*)&kT[1][i4])[2 + e] = a[7];
        ((float*)&vT[0][i4])[e]     = a[8];
        ((float*)&vT[0][i4])[2 + e] = a[9];
        ((float*)&vT[1][i4])[e]     = a[10];
        ((float*)&vT[1][i4])[2 + e] = a[11];
    }
    __syncthreads();

    // ---- attention (bounded scores, exp2-folded) ----
    // wave wv: head h = wv>>1, m-half hs = wv&1 (pairs [hs*49, hs*49+49)).
    // Each lane owns rows {lane, lane+64, lane+128}; every kk/vv read is a
    // full-wave broadcast amortized over 3 rows. Partial (sum,a0,a1) per
    // (h,hs,row) goes to LDS; halves combined in the out-proj phase.
    const int wv = tid >> 6;
    const int lane = tid & 63;
    const int h = wv >> 1;
    const int hs = wv & 1;
    const int i0 = hs * 49;
    const int pbase = h * 392 + hs * 196;
    {
        float2 q[3];
        v2f sum2[3], ac0[3], ac1[3];
        #pragma unroll
        for (int r = 0; r < 3; ++r) {
            q[r] = qs[h][lane + r * 64];
            sum2[r] = (v2f){0.f, 0.f};
            ac0[r]  = (v2f){0.f, 0.f};
            ac1[r]  = (v2f){0.f, 0.f};
        }
        const v4f* kTp = &kT[h][i0];
        const v4f* vTp = &vT[h][i0];
        #pragma unroll 7
        for (int i = 0; i < 49; ++i) {
            const v4f kk = kTp[i];      // ds_read_b128, uniform broadcast
            const v4f vv = vTp[i];
            #pragma unroll
            for (int r = 0; r < 3; ++r) {
                const v2f s = kk.xy * q[r].x + kk.zw * q[r].y;
                v2f e;
                e.x = EXP2F(s.x);
                e.y = EXP2F(s.y);
                sum2[r] += e;
                ac0[r]  += e * vv.xy;
                ac1[r]  += e * vv.zw;
            }
        }
        #pragma unroll
        for (int r = 0; r < 3; ++r) {
            const int l = lane + r * 64;
            psum[pbase + l] = sum2[r].x + sum2[r].y;
            pa0[pbase + l]  = ac0[r].x + ac0[r].y;
            pa1[pbase + l]  = ac1[r].x + ac1[r].y;
        }
    }
    // tail rows 192..195: 16 lanes per row
    {
        const int g = lane >> 4, s16 = lane & 15;
        const int l = 192 + g;
        const float2 q = qs[h][l];
        const v4f* kTp = &kT[h][0];
        const v4f* vTp = &vT[h][0];
        v2f sum2 = {0.f, 0.f}, ac0 = {0.f, 0.f}, ac1 = {0.f, 0.f};
        #pragma unroll
        for (int k = 0; k < 3; ++k) {
            const int i = i0 + s16 + k * 16;
            const v4f kk = kTp[i];
            const v4f vv = vTp[i];
            const v2f s = kk.xy * q.x + kk.zw * q.y;
            v2f e;
            e.x = EXP2F(s.x);
            e.y = EXP2F(s.y);
            sum2 += e;
            ac0 += e * vv.xy;
            ac1 += e * vv.zw;
        }
        if (s16 == 0) {
            const v4f kk = kTp[i0 + 48];
            const v4f vv = vTp[i0 + 48];
            const v2f s = kk.xy * q.x + kk.zw * q.y;
            v2f e;
            e.x = EXP2F(s.x);
            e.y = EXP2F(s.y);
            sum2 += e;
            ac0 += e * vv.xy;
            ac1 += e * vv.zw;
        }
        float sum = sum2.x + sum2.y;
        float a0  = ac0.x + ac0.y;
        float a1  = ac1.x + ac1.y;
        #pragma unroll
        for (int off = 1; off < 16; off <<= 1) {
            sum += __shfl_xor(sum, off);
            a0  += __shfl_xor(a0, off);
            a1  += __shfl_xor(a1, off);
        }
        if (s16 == 0) {
            psum[pbase + l] = sum;
            pa0[pbase + l]  = a0;
            pa1[pbase + l]  = a1;
        }
    }
    __syncthreads();

    // ---- combine halves -> ob (regs), then out-proj + LayerNorm ----
    float f0, f1, f2, f3;
    if (tid < 196) {
        const int l = tid;
        const float s0 = psum[l]       + psum[196 + l];        // head 0
        const float s1 = psum[392 + l] + psum[588 + l];        // head 1
        const float i0h = 1.0f / s0, i1h = 1.0f / s1;
        f0 = (pa0[l]       + pa0[196 + l]) * i0h;
        f1 = (pa1[l]       + pa1[196 + l]) * i0h;
        f2 = (pa0[392 + l] + pa0[588 + l]) * i1h;
        f3 = (pa1[392 + l] + pa1[588 + l]) * i1h;
    }
    __syncthreads();   // all partial reads done before flat overwrites uni
    if (tid < 196) {
        const int l = tid;
        const float e0 = b_out[0] + f0 * w_out[0]  + f1 * w_out[1]  + f2 * w_out[2]  + f3 * w_out[3];
        const float e1 = b_out[1] + f0 * w_out[4]  + f1 * w_out[5]  + f2 * w_out[6]  + f3 * w_out[7];
        const float e2 = b_out[2] + f0 * w_out[8]  + f1 * w_out[9]  + f2 * w_out[10] + f3 * w_out[11];
        const float e3 = b_out[3] + f0 * w_out[12] + f1 * w_out[13] + f2 * w_out[14] + f3 * w_out[15];
        const float mu = 0.25f * (e0 + e1 + e2 + e3);
        const float d0 = e0 - mu, d1 = e1 - mu, d2 = e2 - mu, d3 = e3 - mu;
        const float var = 0.25f * (d0 * d0 + d1 * d1 + d2 * d2 + d3 * d3);
        const float rs = rsqrtf(var + EPSF);
        uni[0 * 196 + l] = d0 * rs * s_lnw[0] + s_lnb[0];
        uni[1 * 196 + l] = d1 * rs * s_lnw[1] + s_lnb[1];
        uni[2 * 196 + l] = d2 * rs * s_lnw[2] + s_lnb[2];
        uni[3 * 196 + l] = d3 * rs * s_lnw[3] + s_lnb[3];
    }
    __syncthreads();

    // ---- final linear (10 x 784), float4 per thread + log_softmax ----
    float part[10];
    #pragma unroll
    for (int j = 0; j < 10; ++j) part[j] = 0.f;
    if (tid < 196) {
        const float4 f = ((const float4*)uni)[tid];
        const float4* lw = (const float4*)lin_w + tid;
        #pragma unroll
        for (int j = 0; j < 10; ++j) {
            const float4 w = lw[j * 196];
            part[j] = f.x * w.x + f.y * w.y + f.z * w.z + f.w * w.w;
        }
    }
    #pragma unroll
    for (int j = 0; j < 10; ++j) {
        float v = part[j];
        #pragma unroll
        for (int off = 32; off > 0; off >>= 1) v += __shfl_down(v, off);
        if (lane == 0) wsum[wv][j] = v;
    }
    __syncthreads();
    if (tid < 10)
        logits_s[tid] = wsum[0][tid] + wsum[1][tid] + wsum[2][tid]
                      + wsum[3][tid] + s_linb[tid];
    __syncthreads();
    if (tid == 0) {
        float mx = logits_s[0];
        #pragma unroll
        for (int j = 1; j < 10; ++j) mx = fmaxf(mx, logits_s[j]);
        float se = 0.f;
        #pragma unroll
        for (int j = 0; j < 10; ++j) se += __expf(logits_s[j] - mx);
        lse_s = mx + __logf(se);
    }
    __syncthreads();
    if (tid < 10) out[(size_t)bid * 10 + tid] = logits_s[tid] - lse_s;
}

extern "C" void kernel_launch(void* const* d_in, const int* in_sizes, int n_in,
                              void* d_out, int out_size, void* d_ws, size_t ws_size,
                              hipStream_t stream) {
    const float* x        = (const float*)d_in[0];
    const float* qparams  = (const float*)d_in[1];
    const float* in_w     = (const float*)d_in[2];
    const float* in_b     = (const float*)d_in[3];
    const float* out_w    = (const float*)d_in[4];
    const float* out_b    = (const float*)d_in[5];
    const float* lnw      = (const float*)d_in[6];
    const float* lnb      = (const float*)d_in[7];
    const float* lin_w    = (const float*)d_in[8];
    const float* lin_b    = (const float*)d_in[9];
    float* out            = (float*)d_out;

    const int B = in_sizes[0] / 784;
    hipLaunchKernelGGL(quanv_fused, dim3(B), dim3(NTHREADS), 0, stream,
                       x, qparams, in_w, in_b, out_w, out_b, lnw, lnb, lin_w, lin_b, out);
}